// Round 9
// baseline (86.196 us; speedup 1.0000x reference)
//
#include <hip/hip_runtime.h>

// SPH pressure-gradient segmented scatter-reduce. i is SORTED.
// R9 = R4's proven body (CHUNK=8, packed pv gather, wave segmented scan,
// unscaled atomics, separate finalize) with exactly two deltas:
//   1. gathers (pv, p_i) issue BEFORE the bulky q/dirs stream loads
//   2. stream loads (i, j, q, dirs) are non-temporal via ext_vector_type
//      (zero reuse -> don't pollute L1/L2, don't contend with gather fills)
// Model being tested: per-CU outstanding-miss pool (MSHR x latency) is the
// limiter; cutting gather queueing latency is the only issue-side lever left.

constexpr int   CHUNK = 8;
constexpr float PI_F  = 3.14159265358979323846f;

typedef float vfloat4 __attribute__((ext_vector_type(4)));
typedef int   vint4   __attribute__((ext_vector_type(4)));

__global__ __launch_bounds__(256) void prep_kernel(
    const float* __restrict__ p,
    const float* __restrict__ V,
    float2*      __restrict__ pv,
    float2*      __restrict__ out,
    int N)
{
    int n = blockIdx.x * blockDim.x + threadIdx.x;
    if (n < N) {
        pv[n]  = make_float2(p[n], V[n]);
        out[n] = make_float2(0.0f, 0.0f);
    }
}

__global__ __launch_bounds__(256) void edge_kernel(
    const int*    __restrict__ ei,
    const int*    __restrict__ ej,
    const float*  __restrict__ dirs,   // [E*2] interleaved x,y
    const float*  __restrict__ qarr,
    const float*  __restrict__ support,
    const float*  __restrict__ p_i,
    const float2* __restrict__ pv,     // packed {p, V}
    float*        __restrict__ acc,    // [N*2], zeroed by prep
    long long E)
{
    long long t    = blockIdx.x * (long long)blockDim.x + threadIdx.x;
    long long base = t * CHUNK;
    const int lane = threadIdx.x & 63;

    int   cur = -1;
    float ax = 0.0f, ay = 0.0f;

    if (base < E) {
        const float h    = support[0];
        const float coef = -20.0f * (7.0f / PI_F) / (h * h * h);

        int ii[CHUNK], jj[CHUNK];
        int nk;

        // ---- epoch 1: index vectors (non-temporal, coalesced) ----
        if (base + CHUNK <= E) {
            vint4 ia = __builtin_nontemporal_load((const vint4*)(ei + base));
            vint4 ib = __builtin_nontemporal_load((const vint4*)(ei + base) + 1);
            vint4 ja = __builtin_nontemporal_load((const vint4*)(ej + base));
            vint4 jb = __builtin_nontemporal_load((const vint4*)(ej + base) + 1);
            ii[0]=ia[0]; ii[1]=ia[1]; ii[2]=ia[2]; ii[3]=ia[3];
            ii[4]=ib[0]; ii[5]=ib[1]; ii[6]=ib[2]; ii[7]=ib[3];
            jj[0]=ja[0]; jj[1]=ja[1]; jj[2]=ja[2]; jj[3]=ja[3];
            jj[4]=jb[0]; jj[5]=jb[1]; jj[6]=jb[2]; jj[7]=jb[3];
            nk = CHUNK;
        } else {
            nk = (int)(E - base);
            #pragma unroll
            for (int k = 0; k < CHUNK; ++k) {
                ii[k] = (k < nk) ? ei[base + k] : 0;
                jj[k] = (k < nk) ? ej[base + k] : 0;
            }
        }

        // ---- epoch 2: random gathers issue FIRST (the long pole; cached) ----
        float2 pvv[CHUNK];
        float  piv[CHUNK];
        #pragma unroll
        for (int k = 0; k < CHUNK; ++k) pvv[k] = pv[jj[k]];
        #pragma unroll
        for (int k = 0; k < CHUNK; ++k) piv[k] = p_i[ii[k]];

        // ---- bulk streams: non-temporal, fly concurrently with gathers ----
        float qq[CHUNK], dxv[CHUNK], dyv[CHUNK];
        if (base + CHUNK <= E) {
            vfloat4 qa = __builtin_nontemporal_load((const vfloat4*)(qarr + base));
            vfloat4 qb = __builtin_nontemporal_load((const vfloat4*)(qarr + base) + 1);
            vfloat4 d0 = __builtin_nontemporal_load((const vfloat4*)(dirs + 2 * base));
            vfloat4 d1 = __builtin_nontemporal_load((const vfloat4*)(dirs + 2 * base) + 1);
            vfloat4 d2 = __builtin_nontemporal_load((const vfloat4*)(dirs + 2 * base) + 2);
            vfloat4 d3 = __builtin_nontemporal_load((const vfloat4*)(dirs + 2 * base) + 3);
            qq[0]=qa[0]; qq[1]=qa[1]; qq[2]=qa[2]; qq[3]=qa[3];
            qq[4]=qb[0]; qq[5]=qb[1]; qq[6]=qb[2]; qq[7]=qb[3];
            dxv[0]=d0[0]; dyv[0]=d0[1]; dxv[1]=d0[2]; dyv[1]=d0[3];
            dxv[2]=d1[0]; dyv[2]=d1[1]; dxv[3]=d1[2]; dyv[3]=d1[3];
            dxv[4]=d2[0]; dyv[4]=d2[1]; dxv[5]=d2[2]; dyv[5]=d2[3];
            dxv[6]=d3[0]; dyv[6]=d3[1]; dxv[7]=d3[2]; dyv[7]=d3[3];
        } else {
            #pragma unroll
            for (int k = 0; k < CHUNK; ++k) {
                qq[k]  = (k < nk) ? qarr[base + k]         : 0.0f;
                dxv[k] = (k < nk) ? dirs[2 * (base + k)]   : 0.0f;
                dyv[k] = (k < nk) ? dirs[2 * (base + k)+1] : 0.0f;
            }
        }

        float w[CHUNK];
        #pragma unroll
        for (int k = 0; k < CHUNK; ++k) {
            float om = 1.0f - qq[k];
            w[k] = (piv[k] + pvv[k].x) * pvv[k].y * (coef * qq[k] * om * om * om);
        }

        // per-thread run-length accumulate; interior flush on segment change
        cur = ii[0];
        #pragma unroll
        for (int k = 0; k < CHUNK; ++k) {
            if (k < nk) {
                if (ii[k] != cur) {
                    atomicAdd(&acc[2 * cur],     ax);
                    atomicAdd(&acc[2 * cur + 1], ay);
                    cur = ii[k];
                    ax = 0.0f; ay = 0.0f;
                }
                ax += w[k] * dxv[k];
                ay += w[k] * dyv[k];
            }
        }
    }

    // wave-level segmented inclusive scan over (cur, ax, ay); keys sorted.
    #pragma unroll
    for (int d = 1; d < 64; d <<= 1) {
        int   oc  = __shfl_up(cur, d);
        float oax = __shfl_up(ax,  d);
        float oay = __shfl_up(ay,  d);
        if (lane >= d && oc == cur) { ax += oax; ay += oay; }
    }
    int nxt = __shfl_down(cur, 1);
    if (cur >= 0 && (lane == 63 || nxt != cur)) {
        atomicAdd(&acc[2 * cur],     ax);
        atomicAdd(&acc[2 * cur + 1], ay);
    }
}

__global__ __launch_bounds__(256) void finalize_kernel(
    float2* __restrict__ out,
    const float* __restrict__ rhoi,
    int N)
{
    int n = blockIdx.x * blockDim.x + threadIdx.x;
    if (n < N) {
        float2 a  = out[n];
        float  sc = -1.0f / rhoi[n];
        out[n] = make_float2(a.x * sc, a.y * sc);
    }
}

extern "C" void kernel_launch(void* const* d_in, const int* in_sizes, int n_in,
                              void* d_out, int out_size, void* d_ws, size_t ws_size,
                              hipStream_t stream)
{
    // 0:i 1:j 2:ri 3:rj 4:Vi 5:Vj 6:distances 7:radialDistances
    // 8:support 9:numParticles 10:eps 11:rhoi 12:rhoj 13:pi 14:pj
    const int*   ei      = (const int*)  d_in[0];
    const int*   ej      = (const int*)  d_in[1];
    const float* Vj      = (const float*)d_in[5];
    const float* dirs    = (const float*)d_in[6];
    const float* qarr    = (const float*)d_in[7];
    const float* support = (const float*)d_in[8];
    const float* rhoi    = (const float*)d_in[11];
    const float* p_i     = (const float*)d_in[13];
    const float* p_j     = (const float*)d_in[14];

    const long long E = in_sizes[0];
    const int       N = in_sizes[11];

    float2* pv = (float2*)d_ws;

    const int block = 256;

    prep_kernel<<<(N + block - 1) / block, block, 0, stream>>>(
        p_j, Vj, pv, (float2*)d_out, N);

    const long long nthreads = (E + CHUNK - 1) / CHUNK;
    const int grid = (int)((nthreads + block - 1) / block);
    edge_kernel<<<grid, block, 0, stream>>>(
        ei, ej, dirs, qarr, support, p_i, pv, (float*)d_out, E);

    finalize_kernel<<<(N + block - 1) / block, block, 0, stream>>>(
        (float2*)d_out, rhoi, N);
}